// Round 4
// baseline (1952.694 us; speedup 1.0000x reference)
//
#include <hip/hip_runtime.h>
#include <hip/hip_bf16.h>
#include <math.h>

#define NR 8192
#define DD 1024

typedef __attribute__((ext_vector_type(8))) short bf16x8;
typedef __attribute__((ext_vector_type(4))) float f32x4;

struct u16x4 { unsigned short x, y, z, w; };

__device__ __forceinline__ unsigned short f2bf(float v) {
    __hip_bfloat16 h = __float2bfloat16(v);
    return *(unsigned short*)&h;
}
__device__ __forceinline__ float bf2f(unsigned short u) {
    __hip_bfloat16 h = *(__hip_bfloat16*)&u;
    return __bfloat162float(h);
}

// async global->LDS, 16B per lane; LDS dest is wave-uniform base + lane*16
__device__ __forceinline__ void dma16(const void* g, void* l) {
    __builtin_amdgcn_global_load_lds(
        (const __attribute__((address_space(1))) unsigned int*)g,
        (__attribute__((address_space(3))) unsigned int*)l, 16, 0, 0);
}

#define LGKM0 asm volatile("s_waitcnt lgkmcnt(0)" ::: "memory")
#define BAR   __builtin_amdgcn_s_barrier()

// ---------------------------------------------------------------------------
// Projection GEMM (fp32, known-good).
// MODE 0: pack per-row records [hi(2048B)|lo(2048B)] into qpack (d_out).
// MODE 1: write khi/klo bf16 arrays (ws).
// ---------------------------------------------------------------------------
template <int MODE>
__global__ __launch_bounds__(256) void proj_gemm(const float* __restrict__ X,
                                                 const float* __restrict__ W,
                                                 char* qpack,
                                                 unsigned short* khi,
                                                 unsigned short* klo) {
    __shared__ float As[16][64];
    __shared__ float Bs[16][64];

    const int tid = threadIdx.x;
    const int tx = tid & 15;
    const int ty = tid >> 4;
    const int m0 = blockIdx.y * 64;
    const int n0 = blockIdx.x * 64;

    const int lm  = tid >> 2;
    const int lk4 = (tid & 3) * 4;
    const int bk  = tid >> 4;
    const int bn4 = (tid & 15) * 4;

    float acc[4][4] = {};

    for (int kb = 0; kb < DD; kb += 16) {
        float4 av = *(const float4*)(X + (size_t)(m0 + lm) * DD + kb + lk4);
        As[lk4 + 0][lm] = av.x;
        As[lk4 + 1][lm] = av.y;
        As[lk4 + 2][lm] = av.z;
        As[lk4 + 3][lm] = av.w;
        *(float4*)&Bs[bk][bn4] =
            *(const float4*)(W + (size_t)(kb + bk) * DD + n0 + bn4);
        __syncthreads();
#pragma unroll
        for (int k = 0; k < 16; ++k) {
            float4 a = *(const float4*)&As[k][ty * 4];
            float4 b = *(const float4*)&Bs[k][tx * 4];
            float aa[4] = {a.x, a.y, a.z, a.w};
            float bb[4] = {b.x, b.y, b.z, b.w};
#pragma unroll
            for (int i = 0; i < 4; ++i)
#pragma unroll
                for (int j = 0; j < 4; ++j) acc[i][j] += aa[i] * bb[j];
        }
        __syncthreads();
    }
#pragma unroll
    for (int i = 0; i < 4; ++i) {
        int row = m0 + ty * 4 + i;
        int col = n0 + tx * 4;
        u16x4 hi, lo;
        float v0 = acc[i][0], v1 = acc[i][1], v2 = acc[i][2], v3 = acc[i][3];
        hi.x = f2bf(v0); lo.x = f2bf(v0 - bf2f(hi.x));
        hi.y = f2bf(v1); lo.y = f2bf(v1 - bf2f(hi.y));
        hi.z = f2bf(v2); lo.z = f2bf(v2 - bf2f(hi.z));
        hi.w = f2bf(v3); lo.w = f2bf(v3 - bf2f(hi.w));
        if (MODE == 0) {
            *(u16x4*)(qpack + (size_t)row * 4096 + col * 2)        = hi;
            *(u16x4*)(qpack + (size_t)row * 4096 + 2048 + col * 2) = lo;
        } else {
            *(u16x4*)(khi + (size_t)row * 1024 + col) = hi;
            *(u16x4*)(klo + (size_t)row * 1024 + col) = lo;
        }
    }
}

// ---------------------------------------------------------------------------
// X^T bf16: XT[1024][8192] = bf16(X)^T  (PV B-operand layout)
// ---------------------------------------------------------------------------
__global__ __launch_bounds__(256) void prep_xt(const float* __restrict__ X,
                                               unsigned short* __restrict__ XT) {
    __shared__ float t[64][65];
    const int r0 = blockIdx.x * 64;
    const int c0 = blockIdx.y * 64;
    const int tid = threadIdx.x;
    const int tr = tid >> 6;
    const int tc = tid & 63;
#pragma unroll
    for (int rep = 0; rep < 16; ++rep) {
        int r = rep * 4 + tr;
        t[r][tc] = X[(size_t)(r0 + r) * DD + c0 + tc];
    }
    __syncthreads();
#pragma unroll
    for (int rep = 0; rep < 16; ++rep) {
        int c = rep * 4 + tr;
        XT[(size_t)(c0 + c) * NR + r0 + tc] = f2bf(t[tc][c]);
    }
}

// ---------------------------------------------------------------------------
// Flash attention v3: BM=64, BN=256, 512 thr = 8 waves (1x8), KV-split.
// All K / XT fragment traffic via per-wave global_load_lds band pipelines
// with counted vmcnt (no VGPR cost, no barriers inside phase loops).
// LDS (160KB), phase-disjoint aliasing:
//   S:       [0,64K) Q chunk (hi|lo, swizzled)   [64K,160K) K bands 8x12K (3 slots x 4K)
//   softmax: [0,2K) smax  [2K,4K) ssum           [64K,96K) P (bf16, swizzled)
//   PV:      bands w<4: [w*16K,+16K)  w>=4: [96K+(w-4)*16K,+16K)   (2 slots x 8K)
// ---------------------------------------------------------------------------
template <bool SPLIT>
__global__ __launch_bounds__(512, 2) void flash3(
        const char* __restrict__ qpk,
        const unsigned short* __restrict__ Khi,
        const unsigned short* __restrict__ Klo,
        const unsigned short* __restrict__ XT,
        float* __restrict__ outp,
        unsigned short* __restrict__ On,
        float* __restrict__ mlbuf) {
    __shared__ __align__(128) char lds[163840];

    const int tid = threadIdx.x;
    const int l   = tid & 63;
    const int w   = tid >> 6;
    const int l15 = l & 15;
    const int lk  = l >> 4;
    const int lq2 = l >> 2;
    const int l3  = l & 3;

    int qb, sp;
    if (SPLIT) { qb = blockIdx.x >> 1; sp = blockIdx.x & 1; }
    else       { qb = blockIdx.x;      sp = 0; }
    const int q0  = qb * 64;
    const int kv0 = SPLIT ? sp * (NR / 2) : 0;
    const int kv1 = SPLIT ? kv0 + (NR / 2) : NR;

    const int kband = 65536 + w * 12288;                       // S K-band base
    const int pvb   = (w < 4) ? w * 16384 : 98304 + (w - 4) * 16384;
    const int swzA  = l15 & 7;                                 // A/P row swizzle

    f32x4 o[4][8];
    float m_run[4][4], l_run[4][4];
#pragma unroll
    for (int mr = 0; mr < 4; ++mr) {
#pragma unroll
        for (int nf = 0; nf < 8; ++nf) o[mr][nf] = f32x4{0.f, 0.f, 0.f, 0.f};
#pragma unroll
        for (int g = 0; g < 4; ++g) { m_run[mr][g] = -3.0e38f; l_run[mr][g] = 0.f; }
    }

    for (int k0 = kv0; k0 < kv1; k0 += 256) {
        // ---- K prologue: issue slices 0,1,2 into slots 0,1,2 (4 DMA each) ----
#pragma unroll
        for (int t = 0; t < 3; ++t) {
#pragma unroll
            for (int i = 0; i < 2; ++i) {
                size_t go = ((size_t)(k0 + w * 32 + i * 16 + lq2) << 10) + t * 32 + l3 * 8;
                dma16(Khi + go, &lds[kband + t * 4096 + i * 1024]);
                dma16(Klo + go, &lds[kband + t * 4096 + 2048 + i * 1024]);
            }
        }

        f32x4 acc[4][2];
#pragma unroll
        for (int mr = 0; mr < 4; ++mr)
#pragma unroll
            for (int nf = 0; nf < 2; ++nf) acc[mr][nf] = f32x4{0.f, 0.f, 0.f, 0.f};

        // ---- S phase: 4 Q-chunks x 8 K-slices ----
#pragma unroll
        for (int c = 0; c < 4; ++c) {
            LGKM0; BAR;   // all waves done with previous chunk's qlds reads
#pragma unroll
            for (int rep = 0; rep < 8; ++rep) {
                int z = rep * 512 + tid;
                int arr = z >> 11;
                int r = (z >> 5) & 63;
                int j = z & 31;
                bf16x8 v = *(const bf16x8*)(qpk + (size_t)(q0 + r) * 4096 +
                                            arr * 2048 + c * 512 + j * 16);
                *(bf16x8*)&lds[arr * 32768 + r * 512 + ((j ^ (r & 7)) << 4)] = v;
            }
            LGKM0; BAR;   // Q chunk visible

#pragma unroll
            for (int ks = 0; ks < 8; ++ks) {
                const int s = c * 8 + ks;
                const int sl = s % 3;
                // wait: slice s landed (per-wave counter)
                if (s <= 29)      asm volatile("s_waitcnt vmcnt(8)" ::: "memory");
                else if (s == 30) asm volatile("s_waitcnt vmcnt(4)" ::: "memory");
                else              asm volatile("s_waitcnt vmcnt(0)" ::: "memory");

                bf16x8 ah[4], al[4], bh[2], bl[2];
#pragma unroll
                for (int mr = 0; mr < 4; ++mr) {
                    int off = (mr * 16 + l15) * 512 + ((((ks << 2) + lk) ^ swzA) << 4);
                    ah[mr] = *(const bf16x8*)&lds[off];
                    al[mr] = *(const bf16x8*)&lds[32768 + off];
                }
#pragma unroll
                for (int nf = 0; nf < 2; ++nf) {
                    int off = kband + sl * 4096 + (nf * 16 + l15) * 64 + lk * 16;
                    bh[nf] = *(const bf16x8*)&lds[off];
                    bl[nf] = *(const bf16x8*)&lds[off + 2048];
                }
                LGKM0;   // frags in regs -> safe to DMA into slot sl

                if (s + 3 < 32) {
#pragma unroll
                    for (int i = 0; i < 2; ++i) {
                        size_t go = ((size_t)(k0 + w * 32 + i * 16 + lq2) << 10) +
                                    (s + 3) * 32 + l3 * 8;
                        dma16(Khi + go, &lds[kband + sl * 4096 + i * 1024]);
                        dma16(Klo + go, &lds[kband + sl * 4096 + 2048 + i * 1024]);
                    }
                }

                __builtin_amdgcn_s_setprio(1);
#pragma unroll
                for (int mr = 0; mr < 4; ++mr)
#pragma unroll
                    for (int nf = 0; nf < 2; ++nf) {
                        acc[mr][nf] = __builtin_amdgcn_mfma_f32_16x16x32_bf16(ah[mr], bh[nf], acc[mr][nf], 0, 0, 0);
                        acc[mr][nf] = __builtin_amdgcn_mfma_f32_16x16x32_bf16(al[mr], bh[nf], acc[mr][nf], 0, 0, 0);
                        acc[mr][nf] = __builtin_amdgcn_mfma_f32_16x16x32_bf16(ah[mr], bl[nf], acc[mr][nf], 0, 0, 0);
                    }
                __builtin_amdgcn_s_setprio(0);
            }
        }

        LGKM0; BAR;   // S done: qlds + K bands dead; smax/P regions writable

#pragma unroll
        for (int mr = 0; mr < 4; ++mr)
#pragma unroll
            for (int nf = 0; nf < 2; ++nf) acc[mr][nf] *= 0.03125f;

        float* smaxf = (float*)&lds[0];
        float* ssumf = (float*)&lds[2048];

        // ---- block row-max ----
#pragma unroll
        for (int mr = 0; mr < 4; ++mr)
#pragma unroll
            for (int g = 0; g < 4; ++g) {
                float m = fmaxf(acc[mr][0][g], acc[mr][1][g]);
#pragma unroll
                for (int msk = 1; msk <= 8; msk <<= 1)
                    m = fmaxf(m, __shfl_xor(m, msk, 64));
                if (l15 == 0) smaxf[(mr * 16 + lk * 4 + g) * 8 + w] = m;
            }
        LGKM0; BAR;

        float m_new[4][4], corr[4][4], psum[4][4];
        bool resc = false;
#pragma unroll
        for (int mr = 0; mr < 4; ++mr)
#pragma unroll
            for (int g = 0; g < 4; ++g) {
                int r = mr * 16 + lk * 4 + g;
                float4 v0 = *(const float4*)&smaxf[r * 8];
                float4 v1 = *(const float4*)&smaxf[r * 8 + 4];
                float mn = fmaxf(fmaxf(fmaxf(v0.x, v0.y), fmaxf(v0.z, v0.w)),
                                 fmaxf(fmaxf(v1.x, v1.y), fmaxf(v1.z, v1.w)));
                if (mn - m_run[mr][g] > 8.0f) {    // defer-max (T13)
                    m_new[mr][g] = mn;
                    corr[mr][g]  = __expf(m_run[mr][g] - mn);
                    resc = true;
                } else {
                    m_new[mr][g] = m_run[mr][g];
                    corr[mr][g]  = 1.0f;
                }
                psum[mr][g] = 0.f;
            }

        // ---- p = exp(s-m), write P (bf16, swizzled), partial sums ----
#pragma unroll
        for (int mr = 0; mr < 4; ++mr)
#pragma unroll
            for (int nf = 0; nf < 2; ++nf)
#pragma unroll
                for (int g = 0; g < 4; ++g) {
                    int r = mr * 16 + lk * 4 + g;
                    float p = __expf(acc[mr][nf][g] - m_new[mr][g]);
                    psum[mr][g] += p;
                    int cL = w * 32 + nf * 16 + l15;
                    *(unsigned short*)&lds[65536 + r * 512 +
                        (((cL >> 3) ^ (r & 7)) << 4) + (cL & 7) * 2] = f2bf(p);
                }
#pragma unroll
        for (int mr = 0; mr < 4; ++mr)
#pragma unroll
            for (int g = 0; g < 4; ++g) {
                float sm = psum[mr][g];
#pragma unroll
                for (int msk = 1; msk <= 8; msk <<= 1) sm += __shfl_xor(sm, msk, 64);
                if (l15 == 0) ssumf[(mr * 16 + lk * 4 + g) * 8 + w] = sm;
            }
        LGKM0; BAR;

#pragma unroll
        for (int mr = 0; mr < 4; ++mr)
#pragma unroll
            for (int g = 0; g < 4; ++g) {
                int r = mr * 16 + lk * 4 + g;
                float4 v0 = *(const float4*)&ssumf[r * 8];
                float4 v1 = *(const float4*)&ssumf[r * 8 + 4];
                float lt = v0.x + v0.y + v0.z + v0.w + v1.x + v1.y + v1.z + v1.w;
                l_run[mr][g] = l_run[mr][g] * corr[mr][g] + lt;
                m_run[mr][g] = m_new[mr][g];
            }
        if (resc) {
#pragma unroll
            for (int mr = 0; mr < 4; ++mr)
#pragma unroll
                for (int nf = 0; nf < 8; ++nf)
#pragma unroll
                    for (int g = 0; g < 4; ++g) o[mr][nf][g] *= corr[mr][g];
        }

        LGKM0; BAR;   // P visible; smax/ssum reads done -> PV bands writable

        // ---- PV: per-wave XT band pipeline, 8 phases ----
#pragma unroll
        for (int t = 0; t < 2; ++t) {
#pragma unroll
            for (int i = 0; i < 8; ++i) {
                size_t go = ((size_t)(w * 128 + i * 16 + lq2) << 13) +
                            k0 + t * 32 + l3 * 8;
                dma16(XT + go, &lds[pvb + t * 8192 + i * 1024]);
            }
        }
#pragma unroll
        for (int j = 0; j < 8; ++j) {
            if (j <= 6) asm volatile("s_waitcnt vmcnt(8)" ::: "memory");
            else        asm volatile("s_waitcnt vmcnt(0)" ::: "memory");

            bf16x8 pa[4], xb[8];
#pragma unroll
            for (int mr = 0; mr < 4; ++mr)
                pa[mr] = *(const bf16x8*)&lds[65536 + (mr * 16 + l15) * 512 +
                                              ((((j << 2) + lk) ^ swzA) << 4)];
#pragma unroll
            for (int nf = 0; nf < 8; ++nf)
                xb[nf] = *(const bf16x8*)&lds[pvb + (j & 1) * 8192 +
                                              (nf * 16 + l15) * 64 + lk * 16];
            LGKM0;   // xb in regs -> safe to DMA into slot j&1

            if (j + 2 < 8) {
#pragma unroll
                for (int i = 0; i < 8; ++i) {
                    size_t go = ((size_t)(w * 128 + i * 16 + lq2) << 13) +
                                k0 + (j + 2) * 32 + l3 * 8;
                    dma16(XT + go, &lds[pvb + (j & 1) * 8192 + i * 1024]);
                }
            }

            __builtin_amdgcn_s_setprio(1);
#pragma unroll
            for (int mr = 0; mr < 4; ++mr)
#pragma unroll
                for (int nf = 0; nf < 8; ++nf)
                    o[mr][nf] = __builtin_amdgcn_mfma_f32_16x16x32_bf16(pa[mr], xb[nf], o[mr][nf], 0, 0, 0);
            __builtin_amdgcn_s_setprio(0);
        }

        LGKM0; BAR;   // PV done: bands/P dead; next k0 may restage
    }

    // ---- epilogue ----
    if (SPLIT) {
#pragma unroll
        for (int mr = 0; mr < 4; ++mr)
#pragma unroll
            for (int g = 0; g < 4; ++g) {
                int r = mr * 16 + lk * 4 + g;
                float inv = 1.0f / l_run[mr][g];
#pragma unroll
                for (int nf = 0; nf < 8; ++nf)
                    On[(size_t)sp * NR * DD + (size_t)(q0 + r) * DD +
                       w * 128 + nf * 16 + l15] = f2bf(o[mr][nf][g] * inv);
                if (w == 0 && l15 == 0) {
                    mlbuf[(size_t)sp * NR + q0 + r]          = m_run[mr][g];
                    mlbuf[2 * NR + (size_t)sp * NR + q0 + r] = l_run[mr][g];
                }
            }
    } else {
#pragma unroll
        for (int mr = 0; mr < 4; ++mr)
#pragma unroll
            for (int g = 0; g < 4; ++g) {
                int r = q0 + mr * 16 + lk * 4 + g;
                float inv = 1.0f / l_run[mr][g];
#pragma unroll
                for (int nf = 0; nf < 8; ++nf)
                    outp[(size_t)r * DD + w * 128 + nf * 16 + l15] = o[mr][nf][g] * inv;
            }
    }
}

// ---------------------------------------------------------------------------
// Combine the two KV-split partials
// ---------------------------------------------------------------------------
__global__ __launch_bounds__(256) void combine2(const unsigned short* __restrict__ On,
                                                const float* __restrict__ mlbuf,
                                                float* __restrict__ outp) {
    const int r = blockIdx.x;
    float m1 = mlbuf[r],          m2 = mlbuf[NR + r];
    float l1 = mlbuf[2 * NR + r], l2 = mlbuf[3 * NR + r];
    float m  = fmaxf(m1, m2);
    float w1 = l1 * __expf(m1 - m);
    float w2 = l2 * __expf(m2 - m);
    float inv = 1.0f / (w1 + w2);
    w1 *= inv; w2 *= inv;
    const int d = threadIdx.x * 4;
    u16x4 a = *(const u16x4*)(On + (size_t)r * DD + d);
    u16x4 b = *(const u16x4*)(On + (size_t)NR * DD + (size_t)r * DD + d);
    float4 v;
    v.x = w1 * bf2f(a.x) + w2 * bf2f(b.x);
    v.y = w1 * bf2f(a.y) + w2 * bf2f(b.y);
    v.z = w1 * bf2f(a.z) + w2 * bf2f(b.z);
    v.w = w1 * bf2f(a.w) + w2 * bf2f(b.w);
    *(float4*)(outp + (size_t)r * DD + d) = v;
}

extern "C" void kernel_launch(void* const* d_in, const int* in_sizes, int n_in,
                              void* d_out, int out_size, void* d_ws, size_t ws_size,
                              hipStream_t stream) {
    const float* X  = (const float*)d_in[0];
    const float* Wq = (const float*)d_in[1];
    const float* Wk = (const float*)d_in[2];

    char* qpack = (char*)d_out;                        // [Qhi|Qlo] 4KB/row
    unsigned short* khi = (unsigned short*)d_ws;       // 16 MiB
    unsigned short* klo = khi + (size_t)NR * DD;       // 16 MiB
    unsigned short* xt  = klo + (size_t)NR * DD;       // 16 MiB
    unsigned short* On  = xt + (size_t)DD * NR;        // 32 MiB (2 splits)
    float* mlbuf        = (float*)(On + (size_t)2 * NR * DD);  // 128 KiB

    const size_t need_split = (size_t)NR * DD * 2 * 3 * 2
                            + (size_t)2 * NR * DD * 2
                            + (size_t)4 * NR * 4;

    dim3 pgrid(DD / 64, NR / 64);
    proj_gemm<0><<<pgrid, 256, 0, stream>>>(X, Wq, qpack, nullptr, nullptr);
    proj_gemm<1><<<pgrid, 256, 0, stream>>>(X, Wk, nullptr, khi, klo);
    prep_xt<<<dim3(NR / 64, DD / 64), 256, 0, stream>>>(X, xt);

    if (ws_size >= need_split) {
        flash3<true><<<NR / 64 * 2, 512, 0, stream>>>(qpack, khi, klo, xt,
                                                      nullptr, On, mlbuf);
        combine2<<<NR, 256, 0, stream>>>(On, mlbuf, (float*)d_out);
    } else {
        flash3<false><<<NR / 64, 512, 0, stream>>>(qpack, khi, klo, xt,
                                                   (float*)d_out, nullptr, nullptr);
    }
}